// Round 1
// baseline (124.401 us; speedup 1.0000x reference)
//
#include <hip/hip_runtime.h>

#define BB 64
#define KK 16
#define LL 16384
#define CAP 2048
#define NROW (BB * KK)   // 1024 rows == grid size

// Self-resetting completion counter for the single-dispatch last-block combine.
// Invariant: 0 at every kernel entry/exit (last block resets it), so hipGraph
// replay across timed iterations is safe.
__device__ unsigned int g_done = 0;

// ---------------------------------------------------------------------------
// ONE dispatch for the whole op (was: memset + mask_stats + loss = 3).
//
// Per block (b,k):
//   * load its logits row fully into registers (64 VGPRs), single pass
//   * load mask row b, segment k (1 float4/thread = 4 KB) -> segment sum /
//     sum-of-squares written to ws (mask is read exactly ONCE grid-wide;
//     0/1 sums are integer-exact in fp32 so downstream math is unchanged)
//   * sparsemax support via candidates {z > zmax-1} (superset of support),
//     fast path: wave-0 bitonic sort + exact reference support test
//   * write deterministic partials (a1 = sum p^2, t2 = sum p*m) to ws
//     -- 1/S is deferred to the combine, so no cross-block stats dependency
//   * threadfence-reduction: last block to finish combines 4096 ws floats,
//     computes inv_s/sumq2 per b, writes the scalar out with a PLAIN store
//     (no atomics on out => no memset; bitwise-deterministic result).
//
// __launch_bounds__(256,4): 128-VGPR budget so the 16x float4 row stays
// register-resident (prior rounds showed the 8-wave default silently spills
// to a two-pass ~1 TB/s kernel). LDS = ~32.2 KB -> still 4 blocks/CU.
// ---------------------------------------------------------------------------
__global__ __launch_bounds__(256, 4) void fused_sparsemax_loss(
    const float* __restrict__ logits, const float* __restrict__ mask,
    float* __restrict__ ws, float* __restrict__ out) {
  int row = blockIdx.x;        // b*K + k
  int b = row >> 4;            // K == 16
  int kseg = row & 15;         // mask segment this block owns
  const float* z = logits + (size_t)row * LL;
  const float* m = mask + (size_t)b * LL;
  const float4* zv = reinterpret_cast<const float4*>(z);
  const float4* mv = reinterpret_cast<const float4*>(m);
  int t = threadIdx.x;
  int wave = t >> 6, lane = t & 63;

  __shared__ float lds_val[CAP];
  __shared__ int   lds_idx[CAP];
  __shared__ float fin[4 * NROW];       // last-block combine staging (16 KB)
  __shared__ int   lds_n;
  __shared__ float lds_f[4], lds_s[4], lds_sq[4];
  __shared__ float red[4], red2[4];
  __shared__ int   lds_last;

  if (t == 0) lds_n = 0;

  // ---- single streaming pass: 16 logits loads + 1 mask-segment load, all
  //      issued before any consumption; row stays register-resident ----
  float4 v[16];
#pragma unroll
  for (int j = 0; j < 16; ++j) v[j] = zv[j * 256 + t];
  float4 w = mv[kseg * 256 + t];   // issued last: consuming v[0] only waits
                                   // for v[0] (in-order vmcnt), w waits vmcnt 0

  float mx0 = -3.0e38f, mx1 = -3.0e38f, mx2 = -3.0e38f, mx3 = -3.0e38f;
#pragma unroll
  for (int j = 0; j < 4; ++j) {
    mx0 = fmaxf(mx0, fmaxf(fmaxf(v[4*j+0].x, v[4*j+0].y), fmaxf(v[4*j+0].z, v[4*j+0].w)));
    mx1 = fmaxf(mx1, fmaxf(fmaxf(v[4*j+1].x, v[4*j+1].y), fmaxf(v[4*j+1].z, v[4*j+1].w)));
    mx2 = fmaxf(mx2, fmaxf(fmaxf(v[4*j+2].x, v[4*j+2].y), fmaxf(v[4*j+2].z, v[4*j+2].w)));
    mx3 = fmaxf(mx3, fmaxf(fmaxf(v[4*j+3].x, v[4*j+3].y), fmaxf(v[4*j+3].z, v[4*j+3].w)));
  }
  float vmax = fmaxf(fmaxf(mx0, mx1), fmaxf(mx2, mx3));
  float ms  = w.x + w.y + w.z + w.w;
  float msq = w.x * w.x + w.y * w.y + w.z * w.z + w.w * w.w;
  for (int off = 32; off; off >>= 1) {
    vmax = fmaxf(vmax, __shfl_xor(vmax, off));
    ms  += __shfl_xor(ms, off);
    msq += __shfl_xor(msq, off);
  }
  if (lane == 0) { lds_f[wave] = vmax; lds_s[wave] = ms; lds_sq[wave] = msq; }
  __syncthreads();
  float zmax = fmaxf(fmaxf(lds_f[0], lds_f[1]), fmaxf(lds_f[2], lds_f[3]));
  float thr = zmax - 1.0f;
  if (t == 0) {
    // mask segment stats -> deterministic ws slots (no zeroing needed)
    ws[2 * NROW + 2 * row]     = lds_s[0] + lds_s[1] + lds_s[2] + lds_s[3];
    ws[2 * NROW + 2 * row + 1] = lds_sq[0] + lds_sq[1] + lds_sq[2] + lds_sq[3];
  }

  // ---- candidate compaction straight from registers ----
#pragma unroll
  for (int j = 0; j < 16; ++j) {
    int base = (j * 256 + t) * 4;
    float vv[4] = {v[j].x, v[j].y, v[j].z, v[j].w};
#pragma unroll
    for (int e = 0; e < 4; ++e) {
      if (vv[e] > thr) {
        int pos = atomicAdd(&lds_n, 1);
        if (pos < CAP) { lds_val[pos] = vv[e]; lds_idx[pos] = base + e; }
      }
    }
  }
  __syncthreads();
  int n = lds_n;

  float a1 = 0.f, t2 = 0.f;    // valid on t==0 after the paths below

  if (n <= 64) {
    // ================= fast path: exact sorted solve on wave 0 ============
    if (wave == 0) {
      float c = (lane < n) ? lds_val[lane] : -3.0e38f;
      // bitonic sort, descending across 64 lanes
#pragma unroll
      for (int size = 2; size <= 64; size <<= 1) {
#pragma unroll
        for (int stride = size >> 1; stride > 0; stride >>= 1) {
          float other = __shfl_xor(c, stride);
          bool dirDesc = ((lane & size) == 0);
          bool takeMax = (dirDesc == ((lane & stride) == 0));
          float mn = fminf(c, other), mxv = fmaxf(c, other);
          c = takeMax ? mxv : mn;
        }
      }
      // inclusive prefix sum of sorted values
      float cum = c;
#pragma unroll
      for (int off = 1; off < 64; off <<= 1) {
        float y = __shfl_up(cum, off);
        if (lane >= off) cum += y;
      }
      // reference support test: 1 + k*z_sorted > cumsum
      bool sup = (lane < n) && (1.0f + (float)(lane + 1) * c > cum);
      unsigned long long bal = __ballot(sup);
      int k = __popcll(bal);              // k >= 1 always (top element)
      float S = sup ? c : 0.f;
      for (int off = 32; off; off >>= 1) S += __shfl_xor(S, off);
      float tau = (S - 1.0f) / (float)k;

      // partials over the (unsorted) candidate list; p == 0 outside it
      float aa1 = 0.f, aa2 = 0.f;
      if (lane < n) {
        float val = lds_val[lane];
        float p = fmaxf(val - tau, 0.f);
        if (p > 0.f) {
          aa1 = p * p;
          aa2 = p * m[lds_idx[lane]];     // raw p*m; 1/S applied in combine
        }
      }
      for (int off = 32; off; off >>= 1) {
        aa1 += __shfl_xor(aa1, off);
        aa2 += __shfl_xor(aa2, off);
      }
      a1 = aa1; t2 = aa2;
    }
  } else if (n <= CAP) {
    // ============ mid path: wave-0 bisection over LDS candidates ==========
    if (wave == 0) {
      int nj = (n + 63) >> 6;
      float lo = thr, hi = zmax;
      for (int it = 0; it < 30; ++it) {
        float mid = 0.5f * (lo + hi);
        float s = 0.f;
        for (int j = 0; j < nj; ++j) {
          int i = j * 64 + lane;
          float cc = (i < n) ? lds_val[i] : -3.0e38f;
          s += fmaxf(cc - mid, 0.f);
        }
        for (int off = 32; off; off >>= 1) s += __shfl_xor(s, off);
        if (s >= 1.0f) lo = mid; else hi = mid;
      }
      float S = 0.f, kc = 0.f;
      for (int j = 0; j < nj; ++j) {
        int i = j * 64 + lane;
        float cc = (i < n) ? lds_val[i] : -3.0e38f;
        if (cc > lo) { S += cc; kc += 1.f; }
      }
      for (int off = 32; off; off >>= 1) {
        S  += __shfl_xor(S, off);
        kc += __shfl_xor(kc, off);
      }
      float tau = (S - 1.0f) / kc;

      float aa1 = 0.f, aa2 = 0.f;
      for (int j = 0; j < nj; ++j) {
        int i = j * 64 + lane;
        if (i < n) {
          float p = fmaxf(lds_val[i] - tau, 0.f);
          if (p > 0.f) {
            aa1 += p * p;
            aa2 += p * m[lds_idx[i]];
          }
        }
      }
      for (int off = 32; off; off >>= 1) {
        aa1 += __shfl_xor(aa1, off);
        aa2 += __shfl_xor(aa2, off);
      }
      a1 = aa1; t2 = aa2;
    }
  } else {
    // ===== slow path (unreachable for this data): block bisection over
    //       global memory re-reads; correctness only ======================
    float lo = thr, hi = zmax;
    for (int it = 0; it < 30; ++it) {
      float mid = 0.5f * (lo + hi);
      float s = 0.f;
      for (int j = 0; j < 16; ++j) {
        float4 vv = zv[j * 256 + t];
        s += fmaxf(vv.x - mid, 0.f) + fmaxf(vv.y - mid, 0.f) +
             fmaxf(vv.z - mid, 0.f) + fmaxf(vv.w - mid, 0.f);
      }
      for (int off = 32; off; off >>= 1) s += __shfl_xor(s, off);
      __syncthreads();
      if (lane == 0) red[wave] = s;
      __syncthreads();
      float tot = red[0] + red[1] + red[2] + red[3];
      if (tot >= 1.0f) lo = mid; else hi = mid;
    }
    float S = 0.f, kc = 0.f;
    for (int j = 0; j < 16; ++j) {
      float4 vv4 = zv[j * 256 + t];
      float vv[4] = {vv4.x, vv4.y, vv4.z, vv4.w};
      for (int e = 0; e < 4; ++e)
        if (vv[e] > lo) { S += vv[e]; kc += 1.f; }
    }
    for (int off = 32; off; off >>= 1) {
      S  += __shfl_xor(S, off);
      kc += __shfl_xor(kc, off);
    }
    __syncthreads();
    if (lane == 0) { red[wave] = S; red2[wave] = kc; }
    __syncthreads();
    S  = red[0] + red[1] + red[2] + red[3];
    kc = red2[0] + red2[1] + red2[2] + red2[3];
    float tau = (S - 1.0f) / kc;

    float aa1 = 0.f, aa2 = 0.f;
    for (int j = 0; j < 16; ++j) {
      int base = (j * 256 + t) * 4;
      float4 vv4 = zv[j * 256 + t];
      float vv[4] = {vv4.x, vv4.y, vv4.z, vv4.w};
      for (int e = 0; e < 4; ++e) {
        float p = fmaxf(vv[e] - tau, 0.f);
        if (p > 0.f) {
          aa1 += p * p;
          aa2 += p * m[base + e];
        }
      }
    }
    for (int off = 32; off; off >>= 1) {
      aa1 += __shfl_xor(aa1, off);
      aa2 += __shfl_xor(aa2, off);
    }
    __syncthreads();
    if (lane == 0) { red[wave] = aa1; red2[wave] = aa2; }
    __syncthreads();
    if (t == 0) {
      a1 = red[0] + red[1] + red[2] + red[3];
      t2 = red2[0] + red2[1] + red2[2] + red2[3];
    }
  }

  // ---- completion protocol: deterministic partials + last-block combine ----
  if (t == 0) {
    ws[2 * row]     = a1;
    ws[2 * row + 1] = t2;
    __threadfence();                          // release ws writes (device scope)
    unsigned old = atomicAdd(&g_done, 1u);    // device-scope RMW at coherent point
    int last = (old == NROW - 1);
    lds_last = last;
    if (last) atomicExch(&g_done, 0u);        // reset for next graph replay
  }
  __syncthreads();

  if (lds_last) {
    __threadfence();                          // acquire: invalidate stale L1/L2
    const float4* wv4 = reinterpret_cast<const float4*>(ws);
    float4* fin4 = reinterpret_cast<float4*>(fin);
#pragma unroll
    for (int j = 0; j < 4; ++j) fin4[j * 256 + t] = wv4[j * 256 + t];
    __syncthreads();

    float acc = 0.f;
    if (t < 64) {                             // one thread per batch row b
      float S = 0.f, SQ = 0.f;
#pragma unroll
      for (int kk = 0; kk < 16; ++kk) {
        S  += fin[2 * NROW + 2 * (t * 16 + kk)];
        SQ += fin[2 * NROW + 2 * (t * 16 + kk) + 1];
      }
      float inv = 1.0f / fmaxf(S, 1e-12f);
      float sumq2 = SQ * inv * inv;
      acc = 16.0f * sumq2;                    // sum q^2 counted once per head
#pragma unroll
      for (int kk = 0; kk < 16; ++kk) {
        float A1 = fin[2 * (t * 16 + kk)];
        float T2 = fin[2 * (t * 16 + kk) + 1];
        acc += A1 - 2.0f * inv * T2;
      }
    }
    if (wave == 0) {                          // t<64 all live in wave 0
      for (int off = 32; off; off >>= 1) acc += __shfl_xor(acc, off);
      if (t == 0) out[0] = acc * (0.5f / (float)(BB * KK));
    }
  }
}

extern "C" void kernel_launch(void* const* d_in, const int* in_sizes, int n_in,
                              void* d_out, int out_size, void* d_ws, size_t ws_size,
                              hipStream_t stream) {
  const float* logits = (const float*)d_in[0];  // (B,K,L) fp32
  const float* mask   = (const float*)d_in[1];  // (B,L)   fp32
  float* ws  = (float*)d_ws;                    // 4*NROW floats = 16 KB used
  float* out = (float*)d_out;                   // scalar fp32

  // single dispatch; no memset (out is written by a plain store from the
  // last-finishing block), no separate stats kernel (mask stats computed
  // as per-block segments, combined in the same dispatch)
  fused_sparsemax_loss<<<NROW, 256, 0, stream>>>(logits, mask, ws, out);
}

// Round 2
// 122.720 us; speedup vs baseline: 1.0137x; 1.0137x over previous
//
#include <hip/hip_runtime.h>

#define BB 64
#define KK 16
#define LL 16384
#define CAP 1024
#define NROW (BB * KK)   // 1024 rows == grid size
#define TPB 512

// ---------------------------------------------------------------------------
// Kernel 1: one block per (b,k) row, 512 threads.  Whole row register-resident
// in 8 float4 (32 VGPRs) -- half the footprint of the 256-thread variant, so
// __launch_bounds__(512,8) (VGPR cap 64) holds it without rematerialization.
// An empty asm "+v" pin after the loads makes the row values opaque defs, so
// the compiler CANNOT silently re-load them (round-1 regression: VGPR=60,
// two-pass re-read, 56us).  Mask row b segment kseg (1 float4 for t<256) is
// folded in: mask is read exactly once grid-wide; 0/1 sums are integer-exact
// in fp32 so stats math is bit-identical to a separate stats kernel.
//
// Outputs (deterministic slot writes, no zeroing needed):
//   ws[2*row], ws[2*row+1]             = a1 (= sum p^2), t2 (= sum p*m)
//   ws[2*NROW+2*row], ws[2*NROW+2*row+1] = segment sum(m), sum(m^2)
// 1/S is deferred to the combine kernel -> no cross-block dependency, no
// fences, no completion counter (round-1's device-scope threadfence +
// serialized g_done atomic across 1024 blocks was the other regression).
// ---------------------------------------------------------------------------
__global__ __launch_bounds__(TPB, 8) void sparsemax_partial(
    const float* __restrict__ logits, const float* __restrict__ mask,
    float* __restrict__ ws) {
  int row = blockIdx.x;        // b*K + k
  int b = row >> 4;            // K == 16
  int kseg = row & 15;         // mask segment this block owns
  const float* z = logits + (size_t)row * LL;
  const float* m = mask + (size_t)b * LL;
  const float4* zv = reinterpret_cast<const float4*>(z);
  const float4* mv = reinterpret_cast<const float4*>(m);
  int t = threadIdx.x;
  int wave = t >> 6, lane = t & 63;

  __shared__ float lds_val[CAP];
  __shared__ int   lds_idx[CAP];
  __shared__ int   lds_n;
  __shared__ float lds_f[8], lds_s[8], lds_sq[8];
  __shared__ float red[8], red2[8];

  if (t == 0) lds_n = 0;

  // ---- single streaming pass: 8 row loads + 1 mask-segment load, all
  //      issued before any consumption ----
  float4 v[8];
#pragma unroll
  for (int j = 0; j < 8; ++j) v[j] = zv[j * TPB + t];
  float4 w = make_float4(0.f, 0.f, 0.f, 0.f);
  if (t < 256) w = mv[kseg * 256 + t];   // 1024 floats = 256 float4

  // pin the row in registers: opaque def forbids rematerialization-by-reload
#pragma unroll
  for (int j = 0; j < 8; ++j)
    asm volatile("" : "+v"(v[j].x), "+v"(v[j].y), "+v"(v[j].z), "+v"(v[j].w));

  float mx0 = -3.0e38f, mx1 = -3.0e38f;
#pragma unroll
  for (int j = 0; j < 4; ++j) {
    mx0 = fmaxf(mx0, fmaxf(fmaxf(v[2*j+0].x, v[2*j+0].y), fmaxf(v[2*j+0].z, v[2*j+0].w)));
    mx1 = fmaxf(mx1, fmaxf(fmaxf(v[2*j+1].x, v[2*j+1].y), fmaxf(v[2*j+1].z, v[2*j+1].w)));
  }
  float vmax = fmaxf(mx0, mx1);
  float ms  = w.x + w.y + w.z + w.w;
  float msq = w.x * w.x + w.y * w.y + w.z * w.z + w.w * w.w;
  for (int off = 32; off; off >>= 1) {
    vmax = fmaxf(vmax, __shfl_xor(vmax, off));
    ms  += __shfl_xor(ms, off);
    msq += __shfl_xor(msq, off);
  }
  if (lane == 0) { lds_f[wave] = vmax; lds_s[wave] = ms; lds_sq[wave] = msq; }
  __syncthreads();
  float zmax = lds_f[0];
#pragma unroll
  for (int ww = 1; ww < 8; ++ww) zmax = fmaxf(zmax, lds_f[ww]);
  float thr = zmax - 1.0f;
  if (t == 0) {
    float S = 0.f, SQ = 0.f;
#pragma unroll
    for (int ww = 0; ww < 8; ++ww) { S += lds_s[ww]; SQ += lds_sq[ww]; }
    ws[2 * NROW + 2 * row]     = S;
    ws[2 * NROW + 2 * row + 1] = SQ;
  }

  // ---- candidate compaction straight from registers (thr >= tau-1 bound:
  //      {z > zmax-1} is a superset of the sparsemax support) ----
#pragma unroll
  for (int j = 0; j < 8; ++j) {
    int base = (j * TPB + t) * 4;
    float vv[4] = {v[j].x, v[j].y, v[j].z, v[j].w};
#pragma unroll
    for (int e = 0; e < 4; ++e) {
      if (vv[e] > thr) {
        int pos = atomicAdd(&lds_n, 1);
        if (pos < CAP) { lds_val[pos] = vv[e]; lds_idx[pos] = base + e; }
      }
    }
  }
  __syncthreads();
  int n = lds_n;

  if (n <= 64) {
    // ================= fast path: exact sorted solve on wave 0 ============
    if (wave == 0) {
      float c = (lane < n) ? lds_val[lane] : -3.0e38f;
      // bitonic sort, descending across 64 lanes
#pragma unroll
      for (int size = 2; size <= 64; size <<= 1) {
#pragma unroll
        for (int stride = size >> 1; stride > 0; stride >>= 1) {
          float other = __shfl_xor(c, stride);
          bool dirDesc = ((lane & size) == 0);
          bool takeMax = (dirDesc == ((lane & stride) == 0));
          float mn = fminf(c, other), mxv = fmaxf(c, other);
          c = takeMax ? mxv : mn;
        }
      }
      // inclusive prefix sum of sorted values
      float cum = c;
#pragma unroll
      for (int off = 1; off < 64; off <<= 1) {
        float y = __shfl_up(cum, off);
        if (lane >= off) cum += y;
      }
      // reference support test: 1 + k*z_sorted > cumsum
      bool sup = (lane < n) && (1.0f + (float)(lane + 1) * c > cum);
      unsigned long long bal = __ballot(sup);
      int k = __popcll(bal);              // k >= 1 always (top element)
      float S = sup ? c : 0.f;
      for (int off = 32; off; off >>= 1) S += __shfl_xor(S, off);
      float tau = (S - 1.0f) / (float)k;

      // partials over the (unsorted) candidate list; p == 0 outside it
      float aa1 = 0.f, aa2 = 0.f;
      if (lane < n) {
        float val = lds_val[lane];
        float p = fmaxf(val - tau, 0.f);
        if (p > 0.f) {
          aa1 = p * p;
          aa2 = p * m[lds_idx[lane]];     // raw p*m; 1/S applied in combine
        }
      }
      for (int off = 32; off; off >>= 1) {
        aa1 += __shfl_xor(aa1, off);
        aa2 += __shfl_xor(aa2, off);
      }
      if (lane == 0) { ws[2 * row] = aa1; ws[2 * row + 1] = aa2; }
    }
  } else if (n <= CAP) {
    // ============ mid path: wave-0 bisection over LDS candidates ==========
    if (wave == 0) {
      int nj = (n + 63) >> 6;
      float lo = thr, hi = zmax;
      for (int it = 0; it < 30; ++it) {
        float mid = 0.5f * (lo + hi);
        float s = 0.f;
        for (int j = 0; j < nj; ++j) {
          int i = j * 64 + lane;
          float cc = (i < n) ? lds_val[i] : -3.0e38f;
          s += fmaxf(cc - mid, 0.f);
        }
        for (int off = 32; off; off >>= 1) s += __shfl_xor(s, off);
        if (s >= 1.0f) lo = mid; else hi = mid;
      }
      float S = 0.f, kc = 0.f;
      for (int j = 0; j < nj; ++j) {
        int i = j * 64 + lane;
        float cc = (i < n) ? lds_val[i] : -3.0e38f;
        if (cc > lo) { S += cc; kc += 1.f; }
      }
      for (int off = 32; off; off >>= 1) {
        S  += __shfl_xor(S, off);
        kc += __shfl_xor(kc, off);
      }
      float tau = (S - 1.0f) / kc;

      float aa1 = 0.f, aa2 = 0.f;
      for (int j = 0; j < nj; ++j) {
        int i = j * 64 + lane;
        if (i < n) {
          float p = fmaxf(lds_val[i] - tau, 0.f);
          if (p > 0.f) {
            aa1 += p * p;
            aa2 += p * m[lds_idx[i]];
          }
        }
      }
      for (int off = 32; off; off >>= 1) {
        aa1 += __shfl_xor(aa1, off);
        aa2 += __shfl_xor(aa2, off);
      }
      if (lane == 0) { ws[2 * row] = aa1; ws[2 * row + 1] = aa2; }
    }
  } else {
    // ===== slow path (unreachable for this data): block bisection over
    //       global memory re-reads; correctness only ======================
    float lo = thr, hi = zmax;
    for (int it = 0; it < 30; ++it) {
      float mid = 0.5f * (lo + hi);
      float s = 0.f;
      for (int j = 0; j < 8; ++j) {
        float4 vv = zv[j * TPB + t];
        s += fmaxf(vv.x - mid, 0.f) + fmaxf(vv.y - mid, 0.f) +
             fmaxf(vv.z - mid, 0.f) + fmaxf(vv.w - mid, 0.f);
      }
      for (int off = 32; off; off >>= 1) s += __shfl_xor(s, off);
      __syncthreads();
      if (lane == 0) red[wave] = s;
      __syncthreads();
      float tot = 0.f;
#pragma unroll
      for (int ww = 0; ww < 8; ++ww) tot += red[ww];
      if (tot >= 1.0f) lo = mid; else hi = mid;
    }
    float S = 0.f, kc = 0.f;
    for (int j = 0; j < 8; ++j) {
      float4 vv4 = zv[j * TPB + t];
      float vv[4] = {vv4.x, vv4.y, vv4.z, vv4.w};
      for (int e = 0; e < 4; ++e)
        if (vv[e] > lo) { S += vv[e]; kc += 1.f; }
    }
    for (int off = 32; off; off >>= 1) {
      S  += __shfl_xor(S, off);
      kc += __shfl_xor(kc, off);
    }
    __syncthreads();
    if (lane == 0) { red[wave] = S; red2[wave] = kc; }
    __syncthreads();
    S = 0.f; kc = 0.f;
#pragma unroll
    for (int ww = 0; ww < 8; ++ww) { S += red[ww]; kc += red2[ww]; }
    float tau = (S - 1.0f) / kc;

    float aa1 = 0.f, aa2 = 0.f;
    for (int j = 0; j < 8; ++j) {
      int base = (j * TPB + t) * 4;
      float4 vv4 = zv[j * TPB + t];
      float vv[4] = {vv4.x, vv4.y, vv4.z, vv4.w};
      for (int e = 0; e < 4; ++e) {
        float p = fmaxf(vv[e] - tau, 0.f);
        if (p > 0.f) {
          aa1 += p * p;
          aa2 += p * m[base + e];
        }
      }
    }
    for (int off = 32; off; off >>= 1) {
      aa1 += __shfl_xor(aa1, off);
      aa2 += __shfl_xor(aa2, off);
    }
    __syncthreads();
    if (lane == 0) { red[wave] = aa1; red2[wave] = aa2; }
    __syncthreads();
    if (t == 0) {
      aa1 = 0.f; aa2 = 0.f;
#pragma unroll
      for (int ww = 0; ww < 8; ++ww) { aa1 += red[ww]; aa2 += red2[ww]; }
      ws[2 * row] = aa1;
      ws[2 * row + 1] = aa2;
    }
  }
}

// ---------------------------------------------------------------------------
// Kernel 2: tiny combine.  One wave; thread t owns batch row b=t.
// Stream order guarantees visibility of kernel-1's ws writes (same mechanism
// the proven 3-dispatch version relied on) -- no fences, no atomics, no
// memset; deterministic plain store to out.
// ---------------------------------------------------------------------------
__global__ __launch_bounds__(64) void combine_kernel(
    const float* __restrict__ ws, float* __restrict__ out) {
  int t = threadIdx.x;   // 64 threads, one per b
  float S = 0.f, SQ = 0.f;
#pragma unroll
  for (int kk = 0; kk < 16; ++kk) {
    S  += ws[2 * NROW + 2 * (t * 16 + kk)];
    SQ += ws[2 * NROW + 2 * (t * 16 + kk) + 1];
  }
  float inv = 1.0f / fmaxf(S, 1e-12f);
  float acc = 16.0f * SQ * inv * inv;        // sum q^2 counted once per head
#pragma unroll
  for (int kk = 0; kk < 16; ++kk) {
    float A1 = ws[2 * (t * 16 + kk)];
    float T2 = ws[2 * (t * 16 + kk) + 1];
    acc += A1 - 2.0f * inv * T2;
  }
  for (int off = 32; off; off >>= 1) acc += __shfl_xor(acc, off);
  if (t == 0) out[0] = acc * (0.5f / (float)(BB * KK));
}

extern "C" void kernel_launch(void* const* d_in, const int* in_sizes, int n_in,
                              void* d_out, int out_size, void* d_ws, size_t ws_size,
                              hipStream_t stream) {
  const float* logits = (const float*)d_in[0];  // (B,K,L) fp32
  const float* mask   = (const float*)d_in[1];  // (B,L)   fp32
  float* ws  = (float*)d_ws;                    // 4*NROW floats = 16 KB used
  float* out = (float*)d_out;                   // scalar fp32

  // two dispatches, no memset: main writes deterministic per-row partials,
  // combine folds them and plain-stores the scalar.
  sparsemax_partial<<<NROW, TPB, 0, stream>>>(logits, mask, ws);
  combine_kernel<<<1, 64, 0, stream>>>(ws, out);
}

// Round 3
// 110.916 us; speedup vs baseline: 1.1216x; 1.1064x over previous
//
#include <hip/hip_runtime.h>

#define BB 64
#define KK 16
#define LL 16384
#define CAP 2048
#define NROW (BB * KK)

// ---------------------------------------------------------------------------
// Kernel 1: per-batch-row mask statistics (proven round-0 kernel, unchanged).
//   stats[2b]   = 1 / max(sum(mask_b), 1e-12)        (q scale)
//   stats[2b+1] = sum(mask_b^2) / max(sum,1e-12)^2   (= sum q^2)
// ---------------------------------------------------------------------------
__global__ __launch_bounds__(256) void mask_stats_kernel(
    const float* __restrict__ mask, float* __restrict__ stats) {
  int b = blockIdx.x;
  const float* m = mask + (size_t)b * LL;
  int t = threadIdx.x;
  float s = 0.f, sq = 0.f;
#pragma unroll
  for (int j = 0; j < 16; ++j) {
    float4 v = reinterpret_cast<const float4*>(m)[j * 256 + t];
    s  += v.x + v.y + v.z + v.w;
    sq += v.x * v.x + v.y * v.y + v.z * v.z + v.w * v.w;
  }
  for (int off = 32; off; off >>= 1) {
    s  += __shfl_xor(s, off);
    sq += __shfl_xor(sq, off);
  }
  __shared__ float ls[4], lsq[4];
  int wave = t >> 6;
  if ((t & 63) == 0) { ls[wave] = s; lsq[wave] = sq; }
  __syncthreads();
  if (t == 0) {
    float S  = ls[0] + ls[1] + ls[2] + ls[3];
    float SQ = lsq[0] + lsq[1] + lsq[2] + lsq[3];
    float inv = 1.0f / fmaxf(S, 1e-12f);
    stats[2 * b]     = inv;
    stats[2 * b + 1] = SQ * inv * inv;
  }
}

// ---------------------------------------------------------------------------
// Kernel 2: one workgroup per (b,k) row.  This is the PROVEN round-0 hot
// kernel: single pass, whole row in 64 VGPRs, __launch_bounds__(256,4)
// (128-VGPR budget) -- the ONLY configuration across three sessions that
// kept the row register-resident (R1: +16KB LDS/protocol -> VGPR=60 remat,
// 56us; R2: 64-cap + asm pin -> spill-everything, VGPR=32, 50MB scratch,
// 49us).  No asm pin; no extra loads; hot path byte-identical to round 0.
//
// ONLY the epilogue differs from round 0: instead of atomicAdd(out, ...)
// (which required a memset dispatch and a stats read), each row writes the
// deterministic partials  ws[2*row] = sum p^2,  ws[2*row+1] = sum p*m  and
// the 1/S scale is deferred to the combine kernel.  This REMOVES the stats
// load + sumq2 from this kernel: register pressure strictly <= round 0.
// ---------------------------------------------------------------------------
__global__ __launch_bounds__(256, 4) void sparsemax_loss_kernel(
    const float* __restrict__ logits, const float* __restrict__ mask,
    float* __restrict__ ws) {
  int row = blockIdx.x;        // b*K + k
  int b = row >> 4;            // K == 16
  const float* z = logits + (size_t)row * LL;
  const float* m = mask + (size_t)b * LL;
  const float4* zv = reinterpret_cast<const float4*>(z);
  int t = threadIdx.x;
  int wave = t >> 6, lane = t & 63;

  __shared__ float lds_val[CAP];
  __shared__ int   lds_idx[CAP];
  __shared__ int   lds_n;
  __shared__ float lds_f[4];

  if (t == 0) lds_n = 0;

  // ---- single streaming pass: all 16 loads independent, issued before any
  //      consumption; row stays register-resident through compaction ----
  float4 v[16];
#pragma unroll
  for (int j = 0; j < 16; ++j) v[j] = zv[j * 256 + t];

  float mx0 = -3.0e38f, mx1 = -3.0e38f, mx2 = -3.0e38f, mx3 = -3.0e38f;
#pragma unroll
  for (int j = 0; j < 4; ++j) {
    mx0 = fmaxf(mx0, fmaxf(fmaxf(v[4*j+0].x, v[4*j+0].y), fmaxf(v[4*j+0].z, v[4*j+0].w)));
    mx1 = fmaxf(mx1, fmaxf(fmaxf(v[4*j+1].x, v[4*j+1].y), fmaxf(v[4*j+1].z, v[4*j+1].w)));
    mx2 = fmaxf(mx2, fmaxf(fmaxf(v[4*j+2].x, v[4*j+2].y), fmaxf(v[4*j+2].z, v[4*j+2].w)));
    mx3 = fmaxf(mx3, fmaxf(fmaxf(v[4*j+3].x, v[4*j+3].y), fmaxf(v[4*j+3].z, v[4*j+3].w)));
  }
  float vmax = fmaxf(fmaxf(mx0, mx1), fmaxf(mx2, mx3));
  for (int off = 32; off; off >>= 1) vmax = fmaxf(vmax, __shfl_xor(vmax, off));
  if (lane == 0) lds_f[wave] = vmax;
  __syncthreads();
  float zmax = fmaxf(fmaxf(lds_f[0], lds_f[1]), fmaxf(lds_f[2], lds_f[3]));
  float thr = zmax - 1.0f;

  // ---- candidate compaction straight from registers ----
#pragma unroll
  for (int j = 0; j < 16; ++j) {
    int base = (j * 256 + t) * 4;
    float vv[4] = {v[j].x, v[j].y, v[j].z, v[j].w};
#pragma unroll
    for (int e = 0; e < 4; ++e) {
      if (vv[e] > thr) {
        int pos = atomicAdd(&lds_n, 1);
        if (pos < CAP) { lds_val[pos] = vv[e]; lds_idx[pos] = base + e; }
      }
    }
  }
  __syncthreads();
  int n = lds_n;

  if (n <= 64) {
    // ================= fast path: exact sorted solve on wave 0 ============
    if (wave == 0) {
      float c = (lane < n) ? lds_val[lane] : -3.0e38f;
      // bitonic sort, descending across 64 lanes
#pragma unroll
      for (int size = 2; size <= 64; size <<= 1) {
#pragma unroll
        for (int stride = size >> 1; stride > 0; stride >>= 1) {
          float other = __shfl_xor(c, stride);
          bool dirDesc = ((lane & size) == 0);
          bool takeMax = (dirDesc == ((lane & stride) == 0));
          float mn = fminf(c, other), mxv = fmaxf(c, other);
          c = takeMax ? mxv : mn;
        }
      }
      // inclusive prefix sum of sorted values
      float cum = c;
#pragma unroll
      for (int off = 1; off < 64; off <<= 1) {
        float y = __shfl_up(cum, off);
        if (lane >= off) cum += y;
      }
      // reference support test: 1 + k*z_sorted > cumsum
      bool sup = (lane < n) && (1.0f + (float)(lane + 1) * c > cum);
      unsigned long long bal = __ballot(sup);
      int k = __popcll(bal);              // k >= 1 always (top element)
      float S = sup ? c : 0.f;
      for (int off = 32; off; off >>= 1) S += __shfl_xor(S, off);
      float tau = (S - 1.0f) / (float)k;

      // partials over the (unsorted) candidate list; p == 0 outside it
      float a1 = 0.f, a2 = 0.f;
      if (lane < n) {
        float val = lds_val[lane];
        float p = fmaxf(val - tau, 0.f);
        if (p > 0.f) {
          a1 = p * p;
          a2 = p * m[lds_idx[lane]];      // raw p*m; 1/S applied in combine
        }
      }
      for (int off = 32; off; off >>= 1) {
        a1 += __shfl_xor(a1, off);
        a2 += __shfl_xor(a2, off);
      }
      if (lane == 0) { ws[2 * row] = a1; ws[2 * row + 1] = a2; }
    }
  } else if (n <= CAP) {
    // ============ mid path: wave-0 bisection over LDS candidates ==========
    if (wave == 0) {
      int nj = (n + 63) >> 6;
      float lo = thr, hi = zmax;
      for (int it = 0; it < 30; ++it) {
        float mid = 0.5f * (lo + hi);
        float s = 0.f;
        for (int j = 0; j < nj; ++j) {
          int i = j * 64 + lane;
          float cc = (i < n) ? lds_val[i] : -3.0e38f;
          s += fmaxf(cc - mid, 0.f);
        }
        for (int off = 32; off; off >>= 1) s += __shfl_xor(s, off);
        if (s >= 1.0f) lo = mid; else hi = mid;
      }
      float S = 0.f, kc = 0.f;
      for (int j = 0; j < nj; ++j) {
        int i = j * 64 + lane;
        float cc = (i < n) ? lds_val[i] : -3.0e38f;
        if (cc > lo) { S += cc; kc += 1.f; }
      }
      for (int off = 32; off; off >>= 1) {
        S  += __shfl_xor(S, off);
        kc += __shfl_xor(kc, off);
      }
      float tau = (S - 1.0f) / kc;

      float a1 = 0.f, a2 = 0.f;
      for (int j = 0; j < nj; ++j) {
        int i = j * 64 + lane;
        if (i < n) {
          float p = fmaxf(lds_val[i] - tau, 0.f);
          if (p > 0.f) {
            a1 += p * p;
            a2 += p * m[lds_idx[i]];
          }
        }
      }
      for (int off = 32; off; off >>= 1) {
        a1 += __shfl_xor(a1, off);
        a2 += __shfl_xor(a2, off);
      }
      if (lane == 0) { ws[2 * row] = a1; ws[2 * row + 1] = a2; }
    }
  } else {
    // ===== slow path (unreachable for this data): block bisection over
    //       global memory re-reads; correctness only ======================
    __shared__ float red[4], red2[4];
    float lo = thr, hi = zmax;
    for (int it = 0; it < 30; ++it) {
      float mid = 0.5f * (lo + hi);
      float s = 0.f;
      for (int j = 0; j < 16; ++j) {
        float4 vv = zv[j * 256 + t];
        s += fmaxf(vv.x - mid, 0.f) + fmaxf(vv.y - mid, 0.f) +
             fmaxf(vv.z - mid, 0.f) + fmaxf(vv.w - mid, 0.f);
      }
      for (int off = 32; off; off >>= 1) s += __shfl_xor(s, off);
      __syncthreads();
      if (lane == 0) red[wave] = s;
      __syncthreads();
      float tot = red[0] + red[1] + red[2] + red[3];
      if (tot >= 1.0f) lo = mid; else hi = mid;
    }
    float S = 0.f, kc = 0.f;
    for (int j = 0; j < 16; ++j) {
      float4 vv4 = zv[j * 256 + t];
      float vv[4] = {vv4.x, vv4.y, vv4.z, vv4.w};
      for (int e = 0; e < 4; ++e)
        if (vv[e] > lo) { S += vv[e]; kc += 1.f; }
    }
    for (int off = 32; off; off >>= 1) {
      S  += __shfl_xor(S, off);
      kc += __shfl_xor(kc, off);
    }
    __syncthreads();
    if (lane == 0) { red[wave] = S; red2[wave] = kc; }
    __syncthreads();
    S  = red[0] + red[1] + red[2] + red[3];
    kc = red2[0] + red2[1] + red2[2] + red2[3];
    float tau = (S - 1.0f) / kc;

    float a1 = 0.f, a2 = 0.f;
    for (int j = 0; j < 16; ++j) {
      int base = (j * 256 + t) * 4;
      float4 vv4 = zv[j * 256 + t];
      float vv[4] = {vv4.x, vv4.y, vv4.z, vv4.w};
      for (int e = 0; e < 4; ++e) {
        float p = fmaxf(vv[e] - tau, 0.f);
        if (p > 0.f) {
          a1 += p * p;
          a2 += p * m[base + e];
        }
      }
    }
    for (int off = 32; off; off >>= 1) {
      a1 += __shfl_xor(a1, off);
      a2 += __shfl_xor(a2, off);
    }
    __syncthreads();
    if (lane == 0) { red[wave] = a1; red2[wave] = a2; }
    __syncthreads();
    if (t == 0) {
      a1 = red[0] + red[1] + red[2] + red[3];
      a2 = red2[0] + red2[1] + red2[2] + red2[3];
      ws[2 * row] = a1;
      ws[2 * row + 1] = a2;
    }
  }
}

// ---------------------------------------------------------------------------
// Kernel 3: tiny combine.  One wave; thread t owns batch row b=t.  Reads the
// 1024 (a1, t2) partials + 64 (inv, sumq2) stats (8.5 KB, L2-resident),
// folds, plain-stores the scalar.  Stream order guarantees visibility of the
// prior kernels' ws writes (kernel-boundary release/acquire) -- no fences,
// no atomics, no memset needed anywhere.
// ---------------------------------------------------------------------------
__global__ __launch_bounds__(64) void combine_kernel(
    const float* __restrict__ ws, const float* __restrict__ stats,
    float* __restrict__ out) {
  int t = threadIdx.x;   // 64 threads, one per b
  float inv   = stats[2 * t];
  float sumq2 = stats[2 * t + 1];
  float acc = 16.0f * sumq2;                 // sum q^2 counted once per head
#pragma unroll
  for (int kk = 0; kk < 16; ++kk) {
    float A1 = ws[2 * (t * 16 + kk)];
    float T2 = ws[2 * (t * 16 + kk) + 1];
    acc += A1 - 2.0f * inv * T2;
  }
  for (int off = 32; off; off >>= 1) acc += __shfl_xor(acc, off);
  if (t == 0) out[0] = acc * (0.5f / (float)(BB * KK));
}

extern "C" void kernel_launch(void* const* d_in, const int* in_sizes, int n_in,
                              void* d_out, int out_size, void* d_ws, size_t ws_size,
                              hipStream_t stream) {
  const float* logits = (const float*)d_in[0];  // (B,K,L) fp32
  const float* mask   = (const float*)d_in[1];  // (B,L)   fp32
  float* ws    = (float*)d_ws;                  // [0, 2*NROW): row partials
  float* stats = (float*)d_ws + 2 * NROW;       // [2*NROW, +2*BB): mask stats
  float* out   = (float*)d_out;                 // scalar fp32

  // three dispatches, NO memset (round-0 had 4): stats + row partials are
  // deterministic slot writes; combine plain-stores the scalar.
  mask_stats_kernel<<<BB, 256, 0, stream>>>(mask, stats);
  sparsemax_loss_kernel<<<NROW, 256, 0, stream>>>(logits, mask, ws);
  combine_kernel<<<1, 64, 0, stream>>>(ws, stats, out);
}